// Round 17
// baseline (773.384 us; speedup 1.0000x reference)
//
#include <hip/hip_runtime.h>

#define LNUM 4
#define DIM 1024
#define NH 16
#define VOCAB 32000
#define SEQ 2048
#define HIDD 2816

typedef _Float16 f16;
typedef _Float16 h8_t __attribute__((ext_vector_type(8)));
typedef _Float16 h4_t __attribute__((ext_vector_type(4)));
typedef float f4_t __attribute__((ext_vector_type(4)));

#define MFMA(a, b, c) __builtin_amdgcn_mfma_f32_16x16x32_f16(a, b, c, 0, 0, 0)

__device__ __forceinline__ void async16(void* lds, const void* g) {
  __builtin_amdgcn_global_load_lds(
      (const __attribute__((address_space(1))) void*)g,
      (__attribute__((address_space(3))) void*)lds, 16, 0, 0);
}

// DPP helpers
template <int N>
__device__ __forceinline__ float ror16(float x) {
  int r = __builtin_amdgcn_update_dpp(0, __builtin_bit_cast(int, x),
                                      0x120 | N, 0xF, 0xF, true);
  return __builtin_bit_cast(float, r);
}
__device__ __forceinline__ float rsum16(float v) {
  v += ror16<1>(v);
  v += ror16<2>(v);
  v += ror16<4>(v);
  v += ror16<8>(v);
  return v;
}
__device__ __forceinline__ float qswap(float x) {
  int r = __builtin_amdgcn_update_dpp(0, __builtin_bit_cast(int, x), 0xB1,
                                      0xF, 0xF, true);
  return __builtin_bit_cast(float, r);
}

// ---- fused per-layer fp32 -> fp16 weight cast (w13 INTERLEAVED) ----
__global__ __launch_bounds__(256) void cast_layer_k(
    const float* __restrict__ wq, const float* __restrict__ wk,
    const float* __restrict__ wv, const float* __restrict__ wo,
    const float* __restrict__ w1, const float* __restrict__ w3,
    const float* __restrict__ w2, f16* __restrict__ wqkv,
    f16* __restrict__ wod, f16* __restrict__ w13, f16* __restrict__ w2d) {
  const int DD4c = DIM * DIM / 4, HD4c = HIDD * DIM / 4;
  int i = blockIdx.x * 256 + threadIdx.x;
  const float* s;
  f16* d;
  int si, di;
  if (i < 3 * DD4c) {
    d = wqkv;
    di = i;
    if (i < DD4c) {
      s = wq; si = i;
    } else if (i < 2 * DD4c) {
      s = wk; si = i - DD4c;
    } else {
      s = wv; si = i - 2 * DD4c;
    }
  } else if (i < 4 * DD4c) {
    s = wo; si = i - 3 * DD4c; d = wod; di = si;
  } else if (i < 4 * DD4c + HD4c) {
    s = w1; si = i - 4 * DD4c; d = w13;
    di = ((si >> 8) << 9) + (si & 255);        // row 2h
  } else if (i < 4 * DD4c + 2 * HD4c) {
    s = w3; si = i - 4 * DD4c - HD4c; d = w13;
    di = ((si >> 8) << 9) + 256 + (si & 255);  // row 2h+1
  } else {
    s = w2; si = i - 4 * DD4c - 2 * HD4c; d = w2d; di = si;
  }
  float4 v = ((const float4*)s)[si];
  ((h4_t*)d)[di] = (h4_t){(f16)v.x, (f16)v.y, (f16)v.z, (f16)v.w};
}

// ---------------- embedding gather ----------------
__global__ __launch_bounds__(256) void embed_k(const int* __restrict__ tok,
                                               const float* __restrict__ emb,
                                               float* __restrict__ h) {
  const int s = blockIdx.x, t = threadIdx.x;
  ((float4*)(h + (size_t)s * DIM))[t] =
      ((const float4*)(emb + (size_t)tok[s] * DIM))[t];
}

// ---------------- rope table ----------------
__global__ void rope_tab_k(float* __restrict__ tab) {
  int i = blockIdx.x * 256 + threadIdx.x;
  if (i >= SEQ * 32) return;
  int s = i >> 5, f = i & 31;
  float inv = powf(10000.f, -(float)f * (1.f / 32.f));
  float a = (float)s * inv;
  float sn, c;
  sincosf(a, &sn, &c);
  tab[i * 2] = c;
  tab[i * 2 + 1] = sn;
}

// ---------------- rmsnorm ----------------
__global__ __launch_bounds__(256) void rmsnorm_k(const float* __restrict__ h,
                                                 const float* __restrict__ w,
                                                 f16* __restrict__ out) {
  const int s = blockIdx.x, t = threadIdx.x;
  float4 v = ((const float4*)(h + (size_t)s * DIM))[t];
  float ss = v.x * v.x + v.y * v.y + v.z * v.z + v.w * v.w;
#pragma unroll
  for (int d = 1; d < 64; d <<= 1) ss += __shfl_xor(ss, d);
  __shared__ float red[4];
  if ((t & 63) == 0) red[t >> 6] = ss;
  __syncthreads();
  float tot = red[0] + red[1] + red[2] + red[3];
  float sc = rsqrtf(tot * (1.f / (float)DIM) + 1e-5f);
  float4 wv = ((const float4*)w)[t];
  ((h4_t*)(out + (size_t)s * DIM))[t] =
      (h4_t){(f16)(v.x * sc * wv.x), (f16)(v.y * sc * wv.y),
             (f16)(v.z * sc * wv.z), (f16)(v.w * sc * wv.w)};
}

// ---- fused: h += p0 + p1, then rmsnorm ----
__global__ __launch_bounds__(256) void rmsnorm_sk(float* __restrict__ h,
                                                  const float* __restrict__ p,
                                                  const float* __restrict__ w,
                                                  f16* __restrict__ out) {
  const int s = blockIdx.x, t = threadIdx.x;
  float4 v = ((const float4*)(h + (size_t)s * DIM))[t];
  float4 a = ((const float4*)(p + (size_t)s * DIM))[t];
  float4 b = ((const float4*)(p + (size_t)SEQ * DIM + (size_t)s * DIM))[t];
  v.x += a.x + b.x;
  v.y += a.y + b.y;
  v.z += a.z + b.z;
  v.w += a.w + b.w;
  ((float4*)(h + (size_t)s * DIM))[t] = v;
  float ss = v.x * v.x + v.y * v.y + v.z * v.z + v.w * v.w;
#pragma unroll
  for (int d = 1; d < 64; d <<= 1) ss += __shfl_xor(ss, d);
  __shared__ float red[4];
  if ((t & 63) == 0) red[t >> 6] = ss;
  __syncthreads();
  float tot = red[0] + red[1] + red[2] + red[3];
  float sc = rsqrtf(tot * (1.f / (float)DIM) + 1e-5f);
  float4 wv = ((const float4*)w)[t];
  ((h4_t*)(out + (size_t)s * DIM))[t] =
      (h4_t){(f16)(v.x * sc * wv.x), (f16)(v.y * sc * wv.y),
             (f16)(v.z * sc * wv.z), (f16)(v.w * sc * wv.w)};
}

// ---- final rmsnorm on row SEQ-1 with split-K fold ----
__global__ __launch_bounds__(256) void final_norm_sk(
    const float* __restrict__ h, const float* __restrict__ p,
    const float* __restrict__ w, float* __restrict__ hn) {
  const int t = threadIdx.x;
  const size_t row = (size_t)(SEQ - 1) * DIM;
  float4 v = ((const float4*)(h + row))[t];
  float4 a = ((const float4*)(p + row))[t];
  float4 b = ((const float4*)(p + (size_t)SEQ * DIM + row))[t];
  v.x += a.x + b.x;
  v.y += a.y + b.y;
  v.z += a.z + b.z;
  v.w += a.w + b.w;
  float ss = v.x * v.x + v.y * v.y + v.z * v.z + v.w * v.w;
#pragma unroll
  for (int d = 1; d < 64; d <<= 1) ss += __shfl_xor(ss, d);
  __shared__ float red[4];
  if ((t & 63) == 0) red[t >> 6] = ss;
  __syncthreads();
  float tot = red[0] + red[1] + red[2] + red[3];
  float sc = rsqrtf(tot * (1.f / (float)DIM) + 1e-5f);
  float4 wv = ((const float4*)w)[t];
  ((float4*)hn)[t] = make_float4(v.x * sc * wv.x, v.y * sc * wv.y,
                                 v.z * sc * wv.z, v.w * sc * wv.w);
}

// ---------------- logits ----------------
__global__ __launch_bounds__(256) void logits_k(const float* __restrict__ hn,
                                                const float* __restrict__ emb,
                                                float* __restrict__ out) {
  const int v = blockIdx.x * 4 + (threadIdx.x >> 6);
  const int lane = threadIdx.x & 63;
  const float4* er = (const float4*)(emb + (size_t)v * DIM);
  const float4* hr = (const float4*)hn;
  float s = 0.f;
#pragma unroll
  for (int i = 0; i < 4; i++) {
    float4 a = er[lane + i * 64];
    float4 b = hr[lane + i * 64];
    s += a.x * b.x + a.y * b.y + a.z * b.z + a.w * b.w;
  }
#pragma unroll
  for (int d = 1; d < 64; d <<= 1) s += __shfl_xor(s, d);
  if (lane == 0) out[v] = s;
}

// ==== 128x128 GEMM pipe: TRIPLE-buffered LDS ring, single barrier per
// K-step, counted vmcnt(4), stage distance 1 (measured-best config).
#define GEMM_PIPE_LOOP(KLEN, LDSTRIDE)                                       \
  {                                                                          \
    async16(lA, gA);                                                         \
    async16(lA + 64 * 32, gA + (size_t)64 * (LDSTRIDE));                     \
    async16(lB, gB);                                                         \
    async16(lB + 64 * 32, gB + (size_t)64 * (LDSTRIDE));                     \
    int sb = 0;                                                              \
    for (int k0 = 0; k0 < (KLEN); k0 += 32) {                                \
      if (k0 + 32 < (KLEN)) {                                                \
        const int nb = (sb == 2) ? 0 : sb + 1;                               \
        async16(lA + nb * 4096, gA + k0 + 32);                               \
        async16(lA + nb * 4096 + 64 * 32,                                    \
                gA + (size_t)64 * (LDSTRIDE) + k0 + 32);                     \
        async16(lB + nb * 4096, gB + k0 + 32);                               \
        async16(lB + nb * 4096 + 64 * 32,                                    \
                gB + (size_t)64 * (LDSTRIDE) + k0 + 32);                     \
        asm volatile("s_waitcnt vmcnt(4)" ::: "memory");                     \
      } else {                                                               \
        asm volatile("s_waitcnt vmcnt(0)" ::: "memory");                     \
      }                                                                      \
      asm volatile("s_barrier" ::: "memory");                                \
      const f16* As_c = As + sb * 4096;                                      \
      const f16* Bs_c = Bs + sb * 4096;                                      \
      h8_t af[4], bfr[4];                                                    \
      _Pragma("unroll") for (int m = 0; m < 4; m++) af[m] =                  \
          *(const h8_t*)(As_c + (wr * 64 + m * 16 + lr) * 32 +               \
                         ((lk ^ sw) << 3));                                  \
      _Pragma("unroll") for (int n = 0; n < 4; n++) bfr[n] =                 \
          *(const h8_t*)(Bs_c + (wc * 64 + n * 16 + lr) * 32 +               \
                         ((lk ^ sw) << 3));                                  \
      _Pragma("unroll") for (int m = 0; m < 4; m++)                          \
          _Pragma("unroll") for (int n = 0; n < 4; n++) acc[m][n] =          \
              MFMA(af[m], bfr[n], acc[m][n]);                                \
      sb = (sb == 2) ? 0 : sb + 1;                                           \
    }                                                                        \
  }

#define GEMM_PREAMBLE(BPTR, KSTRIDE)                                         \
  const int t = threadIdx.x;                                                 \
  const int lane = t & 63;                                                   \
  const int wave = t >> 6;                                                   \
  const int wr = wave >> 1, wc = wave & 1;                                   \
  const int bm = blockIdx.x, bn = blockIdx.y;                                \
  const int lr = lane & 15, lk = lane >> 4;                                  \
  const int sw = (lr >> 1) & 3;                                              \
  const int srow = t >> 2;                                                   \
  const int scol = (((t & 3) ^ ((t >> 3) & 3))) * 8;                         \
  const f16* gA = A + (size_t)(bm * 128 + srow) * (KSTRIDE) + scol;          \
  const f16* gB = (BPTR) + (size_t)(bn * 128 + srow) * (KSTRIDE) + scol;     \
  f16* lA = As + t * 8;                                                      \
  f16* lB = Bs + t * 8;                                                      \
  f4_t acc[4][4];                                                            \
  _Pragma("unroll") for (int m = 0; m < 4; m++)                              \
      _Pragma("unroll") for (int n = 0; n < 4; n++) acc[m][n] = {0.f, 0.f,   \
                                                                 0.f, 0.f};

// ---- QKV GEMM, fused rope + fused V-transpose epilogue ----
__global__ __launch_bounds__(256) void gemm_qkv(const f16* __restrict__ A,
                                                const f16* __restrict__ B,
                                                f16* __restrict__ C,
                                                f16* __restrict__ vT,
                                                const float* __restrict__ tab) {
  const int N = 3 * DIM, K = DIM;
  __shared__ __align__(16) f16 As[3 * 4096];
  __shared__ __align__(16) f16 Bs[3 * 4096];
  GEMM_PREAMBLE(B, K)
  GEMM_PIPE_LOOP(K, K)

  const int orow = bm * 128 + wr * 64 + lk * 4;
  const int ocol = bn * 128 + wc * 64 + lr;
  const float ssign = (lr & 1) ? 1.f : -1.f;
#pragma unroll
  for (int m = 0; m < 4; m++)
#pragma unroll
    for (int n = 0; n < 4; n++) {
      const int c = ocol + n * 16;  // wave-uniform side of 2048
      const int f = (n * 16 + lr) >> 1;
      if (c < 2048) {
#pragma unroll
        for (int j = 0; j < 4; j++) {
          int r = orow + m * 16 + j;
          float sv = acc[m][n][j];
          float pa = qswap(sv);
          float2 cs = ((const float2*)tab)[r * 32 + f];
          sv = sv * cs.x + pa * cs.y * ssign;
          C[(size_t)r * N + c] = (f16)sv;
        }
      } else {
        h4_t pack;
#pragma unroll
        for (int j = 0; j < 4; j++) pack[j] = (f16)acc[m][n][j];
        *(h4_t*)(vT + (size_t)(c - 2048) * SEQ + orow + m * 16) = pack;
      }
    }
}

// ---- FFN-up GEMM over interleaved w13i, fused silu epilogue ----
__global__ __launch_bounds__(256) void gemm_w13i(const f16* __restrict__ A,
                                                 const f16* __restrict__ B,
                                                 f16* __restrict__ T) {
  const int K = DIM;
  __shared__ __align__(16) f16 As[3 * 4096];
  __shared__ __align__(16) f16 Bs[3 * 4096];
  GEMM_PREAMBLE(B, K)
  GEMM_PIPE_LOOP(K, K)

  const int orow = bm * 128 + wr * 64 + lk * 4;
  const int ocol = bn * 128 + wc * 64 + lr;
  const bool even = (lr & 1) == 0;
#pragma unroll
  for (int m = 0; m < 4; m++)
#pragma unroll
    for (int n = 0; n < 4; n++) {
      const int h = (ocol + n * 16) >> 1;
#pragma unroll
      for (int j = 0; j < 4; j++) {
        float g = acc[m][n][j];
        float u = qswap(g);  // even lane <- odd neighbor's u
        float r = g / (1.f + __expf(-g)) * u;
        if (even)
          T[(size_t)(orow + m * 16 + j) * HIDD + h] = (f16)r;
      }
    }
}

// ------- split-K GEMM: partial C slice (fp32) per blockIdx.z -------
__global__ __launch_bounds__(256) void gemm_skp(const f16* __restrict__ A,
                                                const f16* __restrict__ B0,
                                                float* __restrict__ Cp, int N,
                                                int ld, int Ks) {
  __shared__ __align__(16) f16 As[3 * 4096];
  __shared__ __align__(16) f16 Bs[3 * 4096];
  const int bk = blockIdx.z;
  const f16* Aof = A + (size_t)bk * Ks;
  const f16* B = B0 + (size_t)bk * Ks;
  {
    const f16* A = Aof;  // shadow for preamble
    GEMM_PREAMBLE(B, ld)
    GEMM_PIPE_LOOP(Ks, ld)

    float* Cout = Cp + (size_t)bk * gridDim.x * 128 * N;
    const int orow = bm * 128 + wr * 64 + lk * 4;
    const int ocol = bn * 128 + wc * 64 + lr;
#pragma unroll
    for (int m = 0; m < 4; m++)
#pragma unroll
      for (int n = 0; n < 4; n++)
#pragma unroll
        for (int j = 0; j < 4; j++)
          Cout[(size_t)(orow + m * 16 + j) * N + ocol + n * 16] =
              acc[m][n][j];
  }
}

// ---- flash attention, QBLK=64 (K/V reuse), constant-shift softmax ----
// Grid (NH, SEQ/64); qb64 = 31 - blockIdx.y (heavy-first). Each block:
// 64 q-rows, 4 waves KV-split; per tile 2x the MFMA per loaded K/V vs
// the 32-row version -> half the L2 K/V traffic per output element.
// LDS: P 4x8KB + merge 36KB = 68KB -> 2 blocks/CU (512 blocks = all
// resident). ntiles = qb64+1; diagonal tile is the last tile.
__global__ __launch_bounds__(256) void attn_k(const f16* __restrict__ qkv,
                                              const f16* __restrict__ vT,
                                              f16* __restrict__ o) {
  const int hh = blockIdx.x;
  const int qb = 31 - blockIdx.y;  // heavy-first
  const int tid = threadIdx.x;
  const int wave = tid >> 6;
  const int lane = tid & 63;
  const int lr = lane & 15, lk = lane >> 4;
  const int q0 = qb * 64;
  const float C2 = 0.125f * 1.44269504f;
  const float C1 = -3.f * 1.44269504f;
  __shared__ __align__(16) char P[4][8192];  // per-wave P (64x64 f16), swz
  __shared__ float MBl[3][64][16];           // waves 1..3: lsum[4][4]
  __shared__ f16 MBo[3][64][64];             // waves 1..3: normalized o'
  char* Pw = P[wave];

  h8_t qf[4][2];
#pragma unroll
  for (int m = 0; m < 4; m++)
#pragma unroll
    for (int ks = 0; ks < 2; ks++)
      qf[m][ks] = *(const h8_t*)(qkv + (size_t)(q0 + m * 16 + lr) * 3072 +
                                 hh * 64 + ks * 32 + lk * 8);

  float lsum[4][4];
  f4_t oacc[4][4];
#pragma unroll
  for (int m = 0; m < 4; m++)
#pragma unroll
    for (int j = 0; j < 4; j++) lsum[m][j] = 0.f;
#pragma unroll
  for (int m = 0; m < 4; m++)
#pragma unroll
    for (int n = 0; n < 4; n++) oacc[m][n] = {0.f, 0.f, 0.f, 0.f};

  const int ntiles = qb + 1;
  for (int kt = wave; kt < ntiles; kt += 4) {
    f4_t sacc[4][4];
#pragma unroll
    for (int m = 0; m < 4; m++)
#pragma unroll
      for (int n = 0; n < 4; n++) sacc[m][n] = {0.f, 0.f, 0.f, 0.f};
#pragma unroll
    for (int ks = 0; ks < 2; ks++) {
      h8_t kf[4];
#pragma unroll
      for (int n = 0; n < 4; n++)
        kf[n] = *(const h8_t*)(qkv + (size_t)(kt * 64 + n * 16 + lr) * 3072 +
                               1024 + hh * 64 + ks * 32 + lk * 8);
#pragma unroll
      for (int m = 0; m < 4; m++)
#pragma unroll
        for (int n = 0; n < 4; n++)
          sacc[m][n] = MFMA(qf[m][ks], kf[n], sacc[m][n]);
    }
    const bool lastt = (kt == ntiles - 1);
#pragma unroll
    for (int m = 0; m < 4; m++)
#pragma unroll
      for (int j = 0; j < 4; j++) {
        const int r = m * 16 + lk * 4 + j;
        float rs = 0.f;
#pragma unroll
        for (int n = 0; n < 4; n++) {
          float pe;
          if (lastt && (kt * 64 + n * 16 + lr) > (q0 + r))
            pe = 0.f;
          else
            pe = exp2f(__builtin_fmaf(sacc[m][n][j], C2, C1));
          rs += pe;
          const int c = n * 16 + lr;
          const int off = (r * 128 + c * 2) ^ ((r & 7) << 4);
          *(f16*)(Pw + off) = (f16)pe;
        }
        lsum[m][j] += rsum16(rs);
      }
#pragma unroll
    for (int ks = 0; ks < 2; ks++) {
      h8_t pf[4], vf[4];
#pragma unroll
      for (int m = 0; m < 4; m++) {
        int r = m * 16 + lr;
        int off = (r * 128 + ks * 64 + lk * 16) ^ ((r & 7) << 4);
        pf[m] = *(const h8_t*)(Pw + off);
      }
#pragma unroll
      for (int n = 0; n < 4; n++)
        vf[n] = *(const h8_t*)(vT + (size_t)(hh * 64 + n * 16 + lr) * SEQ +
                               kt * 64 + ks * 32 + lk * 8);
#pragma unroll
      for (int m = 0; m < 4; m++)
#pragma unroll
        for (int n = 0; n < 4; n++)
          oacc[m][n] = MFMA(pf[m], vf[n], oacc[m][n]);
    }
  }

  // ---- cross-wave merge: O = sum_w o'_w * l_w / sum_w l_w ----
  if (wave > 0) {
    float* dl = &MBl[wave - 1][lane][0];
    f16* doo = &MBo[wave - 1][lane][0];
#pragma unroll
    for (int m = 0; m < 4; m++)
#pragma unroll
      for (int j = 0; j < 4; j++) {
        dl[m * 4 + j] = lsum[m][j];
        float inv = lsum[m][j] > 0.f ? 1.f / lsum[m][j] : 0.f;
#pragma unroll
        for (int n = 0; n < 4; n++)
          doo[m * 16 + n * 4 + j] = (f16)(oacc[m][n][j] * inv);
      }
  }
  __syncthreads();
  if (wave == 0) {
#pragma unroll
    for (int m = 0; m < 4; m++)
#pragma unroll
      for (int j = 0; j < 4; j++) {
        float L = lsum[m][j];
        float wt[3];
#pragma unroll
        for (int w = 0; w < 3; w++) {
          wt[w] = MBl[w][lane][m * 4 + j];
          L += wt[w];
        }
        float invL = 1.f / L;
#pragma unroll
        for (int n = 0; n < 4; n++) {
          float val = oacc[m][n][j];
#pragma unroll
          for (int w = 0; w < 3; w++)
            val += (float)MBo[w][lane][m * 16 + n * 4 + j] * wt[w];
          o[(size_t)(q0 + m * 16 + lk * 4 + j) * DIM + hh * 64 + n * 16 +
            lr] = (f16)(val * invL);
        }
      }
  }
}

extern "C" void kernel_launch(void* const* d_in, const int* in_sizes, int n_in,
                              void* d_out, int out_size, void* d_ws,
                              size_t ws_size, hipStream_t stream) {
  (void)in_sizes; (void)n_in; (void)out_size; (void)ws_size;
  const int* tokens = (const int*)d_in[0];
  const float* emb = (const float*)d_in[1];
  const float* wq = (const float*)d_in[2];
  const float* wk = (const float*)d_in[3];
  const float* wv = (const float*)d_in[4];
  const float* wo = (const float*)d_in[5];
  const float* w1 = (const float*)d_in[6];
  const float* w2 = (const float*)d_in[7];
  const float* w3 = (const float*)d_in[8];
  const float* anw = (const float*)d_in[9];
  const float* fnw = (const float*)d_in[10];
  const float* finw = (const float*)d_in[11];
  float* out = (float*)d_out;

  char* p = (char*)d_ws;
  auto alloc = [&](size_t bytes) {
    char* r = p;
    p += (bytes + 255) & ~(size_t)255;
    return r;
  };
  f16* wqkv_l = (f16*)alloc((size_t)3 * DIM * DIM * 2);
  f16* wo_l = (f16*)alloc((size_t)DIM * DIM * 2);
  f16* w13_l = (f16*)alloc((size_t)2 * HIDD * DIM * 2);
  f16* w2_l = (f16*)alloc((size_t)DIM * HIDD * 2);
  float* hbuf = (float*)alloc((size_t)SEQ * DIM * 4);
  f16* x_h = (f16*)alloc((size_t)SEQ * DIM * 2);
  f16* qkv_h = (f16*)alloc((size_t)SEQ * 3 * DIM * 2);
  f16* vT_h = (f16*)alloc((size_t)DIM * SEQ * 2);
  f16* o_h = (f16*)alloc((size_t)SEQ * DIM * 2);
  f16* t_h = (f16*)alloc((size_t)SEQ * HIDD * 2);
  float* skbuf = (float*)alloc((size_t)2 * SEQ * DIM * 4);
  float* tab = (float*)alloc((size_t)SEQ * 32 * 2 * 4);
  float* hn = (float*)alloc(4096);

  embed_k<<<SEQ, 256, 0, stream>>>(tokens, emb, hbuf);
  rope_tab_k<<<(SEQ * 32 + 255) / 256, 256, 0, stream>>>(tab);

  const int CAST_BLOCKS = (4 * (DIM * DIM / 4) + 3 * (HIDD * DIM / 4)) / 256;
  for (int l = 0; l < LNUM; l++) {
    const size_t offDD = (size_t)l * DIM * DIM;
    const size_t offHD = (size_t)l * HIDD * DIM;
    cast_layer_k<<<CAST_BLOCKS, 256, 0, stream>>>(
        wq + offDD, wk + offDD, wv + offDD, wo + offDD, w1 + offHD,
        w3 + offHD, w2 + offHD, wqkv_l, wo_l, w13_l, w2_l);

    if (l == 0) {
      rmsnorm_k<<<SEQ, 256, 0, stream>>>(hbuf, anw, x_h);
    } else {
      rmsnorm_sk<<<SEQ, 256, 0, stream>>>(hbuf, skbuf, anw + (size_t)l * DIM,
                                          x_h);
    }
    {
      dim3 g(SEQ / 128, (3 * DIM) / 128);
      gemm_qkv<<<g, 256, 0, stream>>>(x_h, wqkv_l, qkv_h, vT_h, tab);
    }
    {
      dim3 g(NH, SEQ / 64);  // QBLK=64, head-major, heavy-first
      attn_k<<<g, 256, 0, stream>>>(qkv_h, vT_h, o_h);
    }
    {
      // O-proj split-K: K=1024 -> 2x512 (partials folded by rmsnorm_sk)
      dim3 g(SEQ / 128, DIM / 128, 2);
      gemm_skp<<<g, 256, 0, stream>>>(o_h, wo_l, skbuf, DIM, DIM, DIM / 2);
    }
    rmsnorm_sk<<<SEQ, 256, 0, stream>>>(hbuf, skbuf, fnw + (size_t)l * DIM,
                                        x_h);
    {
      // fused W13 (interleaved) + silu
      dim3 g(SEQ / 128, (2 * HIDD) / 128);
      gemm_w13i<<<g, 256, 0, stream>>>(x_h, w13_l, t_h);
    }
    {
      // W2 split-K: K=2816 -> 2x1408 (partials folded by next norm)
      dim3 g(SEQ / 128, DIM / 128, 2);
      gemm_skp<<<g, 256, 0, stream>>>(t_h, w2_l, skbuf, DIM, HIDD, HIDD / 2);
    }
  }
  final_norm_sk<<<1, 256, 0, stream>>>(hbuf, skbuf, finw, hn);
  logits_k<<<VOCAB / 4, 256, 0, stream>>>(hn, emb, out);
}

// Round 18
// 747.981 us; speedup vs baseline: 1.0340x; 1.0340x over previous
//
#include <hip/hip_runtime.h>

#define LNUM 4
#define DIM 1024
#define NH 16
#define VOCAB 32000
#define SEQ 2048
#define HIDD 2816

typedef _Float16 f16;
typedef _Float16 h8_t __attribute__((ext_vector_type(8)));
typedef _Float16 h4_t __attribute__((ext_vector_type(4)));
typedef float f4_t __attribute__((ext_vector_type(4)));

#define MFMA(a, b, c) __builtin_amdgcn_mfma_f32_16x16x32_f16(a, b, c, 0, 0, 0)

__device__ __forceinline__ void async16(void* lds, const void* g) {
  __builtin_amdgcn_global_load_lds(
      (const __attribute__((address_space(1))) void*)g,
      (__attribute__((address_space(3))) void*)lds, 16, 0, 0);
}

// DPP helpers
template <int N>
__device__ __forceinline__ float ror16(float x) {
  int r = __builtin_amdgcn_update_dpp(0, __builtin_bit_cast(int, x),
                                      0x120 | N, 0xF, 0xF, true);
  return __builtin_bit_cast(float, r);
}
__device__ __forceinline__ float rsum16(float v) {
  v += ror16<1>(v);
  v += ror16<2>(v);
  v += ror16<4>(v);
  v += ror16<8>(v);
  return v;
}
__device__ __forceinline__ float qswap(float x) {
  int r = __builtin_amdgcn_update_dpp(0, __builtin_bit_cast(int, x), 0xB1,
                                      0xF, 0xF, true);
  return __builtin_bit_cast(float, r);
}

// ---- fused per-layer fp32 -> fp16 weight cast (w13 INTERLEAVED) ----
__global__ __launch_bounds__(256) void cast_layer_k(
    const float* __restrict__ wq, const float* __restrict__ wk,
    const float* __restrict__ wv, const float* __restrict__ wo,
    const float* __restrict__ w1, const float* __restrict__ w3,
    const float* __restrict__ w2, f16* __restrict__ wqkv,
    f16* __restrict__ wod, f16* __restrict__ w13, f16* __restrict__ w2d) {
  const int DD4c = DIM * DIM / 4, HD4c = HIDD * DIM / 4;
  int i = blockIdx.x * 256 + threadIdx.x;
  const float* s;
  f16* d;
  int si, di;
  if (i < 3 * DD4c) {
    d = wqkv;
    di = i;
    if (i < DD4c) {
      s = wq; si = i;
    } else if (i < 2 * DD4c) {
      s = wk; si = i - DD4c;
    } else {
      s = wv; si = i - 2 * DD4c;
    }
  } else if (i < 4 * DD4c) {
    s = wo; si = i - 3 * DD4c; d = wod; di = si;
  } else if (i < 4 * DD4c + HD4c) {
    s = w1; si = i - 4 * DD4c; d = w13;
    di = ((si >> 8) << 9) + (si & 255);        // row 2h
  } else if (i < 4 * DD4c + 2 * HD4c) {
    s = w3; si = i - 4 * DD4c - HD4c; d = w13;
    di = ((si >> 8) << 9) + 256 + (si & 255);  // row 2h+1
  } else {
    s = w2; si = i - 4 * DD4c - 2 * HD4c; d = w2d; di = si;
  }
  float4 v = ((const float4*)s)[si];
  ((h4_t*)d)[di] = (h4_t){(f16)v.x, (f16)v.y, (f16)v.z, (f16)v.w};
}

// ---------------- embedding gather ----------------
__global__ __launch_bounds__(256) void embed_k(const int* __restrict__ tok,
                                               const float* __restrict__ emb,
                                               float* __restrict__ h) {
  const int s = blockIdx.x, t = threadIdx.x;
  ((float4*)(h + (size_t)s * DIM))[t] =
      ((const float4*)(emb + (size_t)tok[s] * DIM))[t];
}

// ---------------- rope table ----------------
__global__ void rope_tab_k(float* __restrict__ tab) {
  int i = blockIdx.x * 256 + threadIdx.x;
  if (i >= SEQ * 32) return;
  int s = i >> 5, f = i & 31;
  float inv = powf(10000.f, -(float)f * (1.f / 32.f));
  float a = (float)s * inv;
  float sn, c;
  sincosf(a, &sn, &c);
  tab[i * 2] = c;
  tab[i * 2 + 1] = sn;
}

// ---------------- rmsnorm ----------------
__global__ __launch_bounds__(256) void rmsnorm_k(const float* __restrict__ h,
                                                 const float* __restrict__ w,
                                                 f16* __restrict__ out) {
  const int s = blockIdx.x, t = threadIdx.x;
  float4 v = ((const float4*)(h + (size_t)s * DIM))[t];
  float ss = v.x * v.x + v.y * v.y + v.z * v.z + v.w * v.w;
#pragma unroll
  for (int d = 1; d < 64; d <<= 1) ss += __shfl_xor(ss, d);
  __shared__ float red[4];
  if ((t & 63) == 0) red[t >> 6] = ss;
  __syncthreads();
  float tot = red[0] + red[1] + red[2] + red[3];
  float sc = rsqrtf(tot * (1.f / (float)DIM) + 1e-5f);
  float4 wv = ((const float4*)w)[t];
  ((h4_t*)(out + (size_t)s * DIM))[t] =
      (h4_t){(f16)(v.x * sc * wv.x), (f16)(v.y * sc * wv.y),
             (f16)(v.z * sc * wv.z), (f16)(v.w * sc * wv.w)};
}

// ---- fused: h += p0 + p1, then rmsnorm ----
__global__ __launch_bounds__(256) void rmsnorm_sk(float* __restrict__ h,
                                                  const float* __restrict__ p,
                                                  const float* __restrict__ w,
                                                  f16* __restrict__ out) {
  const int s = blockIdx.x, t = threadIdx.x;
  float4 v = ((const float4*)(h + (size_t)s * DIM))[t];
  float4 a = ((const float4*)(p + (size_t)s * DIM))[t];
  float4 b = ((const float4*)(p + (size_t)SEQ * DIM + (size_t)s * DIM))[t];
  v.x += a.x + b.x;
  v.y += a.y + b.y;
  v.z += a.z + b.z;
  v.w += a.w + b.w;
  ((float4*)(h + (size_t)s * DIM))[t] = v;
  float ss = v.x * v.x + v.y * v.y + v.z * v.z + v.w * v.w;
#pragma unroll
  for (int d = 1; d < 64; d <<= 1) ss += __shfl_xor(ss, d);
  __shared__ float red[4];
  if ((t & 63) == 0) red[t >> 6] = ss;
  __syncthreads();
  float tot = red[0] + red[1] + red[2] + red[3];
  float sc = rsqrtf(tot * (1.f / (float)DIM) + 1e-5f);
  float4 wv = ((const float4*)w)[t];
  ((h4_t*)(out + (size_t)s * DIM))[t] =
      (h4_t){(f16)(v.x * sc * wv.x), (f16)(v.y * sc * wv.y),
             (f16)(v.z * sc * wv.z), (f16)(v.w * sc * wv.w)};
}

// ---- final rmsnorm on row SEQ-1 with split-K fold ----
__global__ __launch_bounds__(256) void final_norm_sk(
    const float* __restrict__ h, const float* __restrict__ p,
    const float* __restrict__ w, float* __restrict__ hn) {
  const int t = threadIdx.x;
  const size_t row = (size_t)(SEQ - 1) * DIM;
  float4 v = ((const float4*)(h + row))[t];
  float4 a = ((const float4*)(p + row))[t];
  float4 b = ((const float4*)(p + (size_t)SEQ * DIM + row))[t];
  v.x += a.x + b.x;
  v.y += a.y + b.y;
  v.z += a.z + b.z;
  v.w += a.w + b.w;
  float ss = v.x * v.x + v.y * v.y + v.z * v.z + v.w * v.w;
#pragma unroll
  for (int d = 1; d < 64; d <<= 1) ss += __shfl_xor(ss, d);
  __shared__ float red[4];
  if ((t & 63) == 0) red[t >> 6] = ss;
  __syncthreads();
  float tot = red[0] + red[1] + red[2] + red[3];
  float sc = rsqrtf(tot * (1.f / (float)DIM) + 1e-5f);
  float4 wv = ((const float4*)w)[t];
  ((float4*)hn)[t] = make_float4(v.x * sc * wv.x, v.y * sc * wv.y,
                                 v.z * sc * wv.z, v.w * sc * wv.w);
}

// ---------------- logits ----------------
__global__ __launch_bounds__(256) void logits_k(const float* __restrict__ hn,
                                                const float* __restrict__ emb,
                                                float* __restrict__ out) {
  const int v = blockIdx.x * 4 + (threadIdx.x >> 6);
  const int lane = threadIdx.x & 63;
  const float4* er = (const float4*)(emb + (size_t)v * DIM);
  const float4* hr = (const float4*)hn;
  float s = 0.f;
#pragma unroll
  for (int i = 0; i < 4; i++) {
    float4 a = er[lane + i * 64];
    float4 b = hr[lane + i * 64];
    s += a.x * b.x + a.y * b.y + a.z * b.z + a.w * b.w;
  }
#pragma unroll
  for (int d = 1; d < 64; d <<= 1) s += __shfl_xor(s, d);
  if (lane == 0) out[v] = s;
}

// ==== 128x128 GEMM pipe: TRIPLE-buffered LDS ring, single barrier per
// K-step, counted vmcnt(4), stage distance 1 (measured-best config).
#define GEMM_PIPE_LOOP(KLEN, LDSTRIDE)                                       \
  {                                                                          \
    async16(lA, gA);                                                         \
    async16(lA + 64 * 32, gA + (size_t)64 * (LDSTRIDE));                     \
    async16(lB, gB);                                                         \
    async16(lB + 64 * 32, gB + (size_t)64 * (LDSTRIDE));                     \
    int sb = 0;                                                              \
    for (int k0 = 0; k0 < (KLEN); k0 += 32) {                                \
      if (k0 + 32 < (KLEN)) {                                                \
        const int nb = (sb == 2) ? 0 : sb + 1;                               \
        async16(lA + nb * 4096, gA + k0 + 32);                               \
        async16(lA + nb * 4096 + 64 * 32,                                    \
                gA + (size_t)64 * (LDSTRIDE) + k0 + 32);                     \
        async16(lB + nb * 4096, gB + k0 + 32);                               \
        async16(lB + nb * 4096 + 64 * 32,                                    \
                gB + (size_t)64 * (LDSTRIDE) + k0 + 32);                     \
        asm volatile("s_waitcnt vmcnt(4)" ::: "memory");                     \
      } else {                                                               \
        asm volatile("s_waitcnt vmcnt(0)" ::: "memory");                     \
      }                                                                      \
      asm volatile("s_barrier" ::: "memory");                                \
      const f16* As_c = As + sb * 4096;                                      \
      const f16* Bs_c = Bs + sb * 4096;                                      \
      h8_t af[4], bfr[4];                                                    \
      _Pragma("unroll") for (int m = 0; m < 4; m++) af[m] =                  \
          *(const h8_t*)(As_c + (wr * 64 + m * 16 + lr) * 32 +               \
                         ((lk ^ sw) << 3));                                  \
      _Pragma("unroll") for (int n = 0; n < 4; n++) bfr[n] =                 \
          *(const h8_t*)(Bs_c + (wc * 64 + n * 16 + lr) * 32 +               \
                         ((lk ^ sw) << 3));                                  \
      _Pragma("unroll") for (int m = 0; m < 4; m++)                          \
          _Pragma("unroll") for (int n = 0; n < 4; n++) acc[m][n] =          \
              MFMA(af[m], bfr[n], acc[m][n]);                                \
      sb = (sb == 2) ? 0 : sb + 1;                                           \
    }                                                                        \
  }

#define GEMM_PREAMBLE(BPTR, KSTRIDE)                                         \
  const int t = threadIdx.x;                                                 \
  const int lane = t & 63;                                                   \
  const int wave = t >> 6;                                                   \
  const int wr = wave >> 1, wc = wave & 1;                                   \
  const int bm = blockIdx.x, bn = blockIdx.y;                                \
  const int lr = lane & 15, lk = lane >> 4;                                  \
  const int sw = (lr >> 1) & 3;                                              \
  const int srow = t >> 2;                                                   \
  const int scol = (((t & 3) ^ ((t >> 3) & 3))) * 8;                         \
  const f16* gA = A + (size_t)(bm * 128 + srow) * (KSTRIDE) + scol;          \
  const f16* gB = (BPTR) + (size_t)(bn * 128 + srow) * (KSTRIDE) + scol;     \
  f16* lA = As + t * 8;                                                      \
  f16* lB = Bs + t * 8;                                                      \
  f4_t acc[4][4];                                                            \
  _Pragma("unroll") for (int m = 0; m < 4; m++)                              \
      _Pragma("unroll") for (int n = 0; n < 4; n++) acc[m][n] = {0.f, 0.f,   \
                                                                 0.f, 0.f};

// ---- QKV GEMM, fused rope + fused V-transpose epilogue ----
__global__ __launch_bounds__(256) void gemm_qkv(const f16* __restrict__ A,
                                                const f16* __restrict__ B,
                                                f16* __restrict__ C,
                                                f16* __restrict__ vT,
                                                const float* __restrict__ tab) {
  const int N = 3 * DIM, K = DIM;
  __shared__ __align__(16) f16 As[3 * 4096];
  __shared__ __align__(16) f16 Bs[3 * 4096];
  GEMM_PREAMBLE(B, K)
  GEMM_PIPE_LOOP(K, K)

  const int orow = bm * 128 + wr * 64 + lk * 4;
  const int ocol = bn * 128 + wc * 64 + lr;
  const float ssign = (lr & 1) ? 1.f : -1.f;
#pragma unroll
  for (int m = 0; m < 4; m++)
#pragma unroll
    for (int n = 0; n < 4; n++) {
      const int c = ocol + n * 16;  // wave-uniform side of 2048
      const int f = (n * 16 + lr) >> 1;
      if (c < 2048) {
#pragma unroll
        for (int j = 0; j < 4; j++) {
          int r = orow + m * 16 + j;
          float sv = acc[m][n][j];
          float pa = qswap(sv);
          float2 cs = ((const float2*)tab)[r * 32 + f];
          sv = sv * cs.x + pa * cs.y * ssign;
          C[(size_t)r * N + c] = (f16)sv;
        }
      } else {
        h4_t pack;
#pragma unroll
        for (int j = 0; j < 4; j++) pack[j] = (f16)acc[m][n][j];
        *(h4_t*)(vT + (size_t)(c - 2048) * SEQ + orow + m * 16) = pack;
      }
    }
}

// ---- FFN-up GEMM over interleaved w13i, fused silu epilogue ----
__global__ __launch_bounds__(256) void gemm_w13i(const f16* __restrict__ A,
                                                 const f16* __restrict__ B,
                                                 f16* __restrict__ T) {
  const int K = DIM;
  __shared__ __align__(16) f16 As[3 * 4096];
  __shared__ __align__(16) f16 Bs[3 * 4096];
  GEMM_PREAMBLE(B, K)
  GEMM_PIPE_LOOP(K, K)

  const int orow = bm * 128 + wr * 64 + lk * 4;
  const int ocol = bn * 128 + wc * 64 + lr;
  const bool even = (lr & 1) == 0;
#pragma unroll
  for (int m = 0; m < 4; m++)
#pragma unroll
    for (int n = 0; n < 4; n++) {
      const int h = (ocol + n * 16) >> 1;
#pragma unroll
      for (int j = 0; j < 4; j++) {
        float g = acc[m][n][j];
        float u = qswap(g);  // even lane <- odd neighbor's u
        float r = g / (1.f + __expf(-g)) * u;
        if (even)
          T[(size_t)(orow + m * 16 + j) * HIDD + h] = (f16)r;
      }
    }
}

// ------- split-K GEMM: partial C slice (fp32) per blockIdx.z -------
__global__ __launch_bounds__(256) void gemm_skp(const f16* __restrict__ A,
                                                const f16* __restrict__ B0,
                                                float* __restrict__ Cp, int N,
                                                int ld, int Ks) {
  __shared__ __align__(16) f16 As[3 * 4096];
  __shared__ __align__(16) f16 Bs[3 * 4096];
  const int bk = blockIdx.z;
  const f16* Aof = A + (size_t)bk * Ks;
  const f16* B = B0 + (size_t)bk * Ks;
  {
    const f16* A = Aof;  // shadow for preamble
    GEMM_PREAMBLE(B, ld)
    GEMM_PIPE_LOOP(Ks, ld)

    float* Cout = Cp + (size_t)bk * gridDim.x * 128 * N;
    const int orow = bm * 128 + wr * 64 + lk * 4;
    const int ocol = bn * 128 + wc * 64 + lr;
#pragma unroll
    for (int m = 0; m < 4; m++)
#pragma unroll
      for (int n = 0; n < 4; n++)
#pragma unroll
        for (int j = 0; j < 4; j++)
          Cout[(size_t)(orow + m * 16 + j) * N + ocol + n * 16] =
              acc[m][n][j];
  }
}

// ---------------- flash attention (constant-shift softmax) ------------
__global__ __launch_bounds__(256) void attn_k(const f16* __restrict__ qkv,
                                              const f16* __restrict__ vT,
                                              f16* __restrict__ o) {
  const int hh = blockIdx.x;
  const int qb = 63 - blockIdx.y;  // heavy-first
  const int tid = threadIdx.x;
  const int wave = tid >> 6;
  const int lane = tid & 63;
  const int lr = lane & 15, lk = lane >> 4;
  const int q0 = qb * 32;
  const float C2 = 0.125f * 1.44269504f;
  const float C1 = -3.f * 1.44269504f;
  __shared__ __align__(16) char P[4][4096];
  __shared__ float MBl[3][64][8];
  __shared__ f16 MBo[3][64][32];
  char* Pw = P[wave];

  h8_t qf[2][2];
#pragma unroll
  for (int m = 0; m < 2; m++)
#pragma unroll
    for (int ks = 0; ks < 2; ks++)
      qf[m][ks] = *(const h8_t*)(qkv + (size_t)(q0 + m * 16 + lr) * 3072 +
                                 hh * 64 + ks * 32 + lk * 8);

  float lsum[2][4];
  f4_t oacc[2][4];
#pragma unroll
  for (int m = 0; m < 2; m++)
#pragma unroll
    for (int j = 0; j < 4; j++) lsum[m][j] = 0.f;
#pragma unroll
  for (int m = 0; m < 2; m++)
#pragma unroll
    for (int n = 0; n < 4; n++) oacc[m][n] = {0.f, 0.f, 0.f, 0.f};

  const int ntiles = (qb >> 1) + 1;
  for (int kt = wave; kt < ntiles; kt += 4) {
    f4_t sacc[2][4];
#pragma unroll
    for (int m = 0; m < 2; m++)
#pragma unroll
      for (int n = 0; n < 4; n++) sacc[m][n] = {0.f, 0.f, 0.f, 0.f};
#pragma unroll
    for (int ks = 0; ks < 2; ks++) {
      h8_t kf[4];
#pragma unroll
      for (int n = 0; n < 4; n++)
        kf[n] = *(const h8_t*)(qkv + (size_t)(kt * 64 + n * 16 + lr) * 3072 +
                               1024 + hh * 64 + ks * 32 + lk * 8);
#pragma unroll
      for (int m = 0; m < 2; m++)
#pragma unroll
        for (int n = 0; n < 4; n++)
          sacc[m][n] = MFMA(qf[m][ks], kf[n], sacc[m][n]);
    }
    const bool lastt = (kt == ntiles - 1);
#pragma unroll
    for (int m = 0; m < 2; m++)
#pragma unroll
      for (int j = 0; j < 4; j++) {
        const int r = m * 16 + lk * 4 + j;
        float rs = 0.f;
#pragma unroll
        for (int n = 0; n < 4; n++) {
          float pe;
          if (lastt && (kt * 64 + n * 16 + lr) > (q0 + r))
            pe = 0.f;
          else
            pe = exp2f(__builtin_fmaf(sacc[m][n][j], C2, C1));
          rs += pe;
          const int c = n * 16 + lr;
          const int off = (r * 128 + c * 2) ^ ((r & 7) << 4);
          *(f16*)(Pw + off) = (f16)pe;
        }
        lsum[m][j] += rsum16(rs);
      }
#pragma unroll
    for (int ks = 0; ks < 2; ks++) {
      h8_t pf[2], vf[4];
#pragma unroll
      for (int m = 0; m < 2; m++) {
        int r = m * 16 + lr;
        int off = (r * 128 + ks * 64 + lk * 16) ^ ((r & 7) << 4);
        pf[m] = *(const h8_t*)(Pw + off);
      }
#pragma unroll
      for (int n = 0; n < 4; n++)
        vf[n] = *(const h8_t*)(vT + (size_t)(hh * 64 + n * 16 + lr) * SEQ +
                               kt * 64 + ks * 32 + lk * 8);
#pragma unroll
      for (int m = 0; m < 2; m++)
#pragma unroll
        for (int n = 0; n < 4; n++)
          oacc[m][n] = MFMA(pf[m], vf[n], oacc[m][n]);
    }
  }

  if (wave > 0) {
    float* dl = &MBl[wave - 1][lane][0];
    f16* doo = &MBo[wave - 1][lane][0];
#pragma unroll
    for (int m = 0; m < 2; m++)
#pragma unroll
      for (int j = 0; j < 4; j++) {
        dl[m * 4 + j] = lsum[m][j];
        float inv = lsum[m][j] > 0.f ? 1.f / lsum[m][j] : 0.f;
#pragma unroll
        for (int n = 0; n < 4; n++)
          doo[m * 16 + n * 4 + j] = (f16)(oacc[m][n][j] * inv);
      }
  }
  __syncthreads();
  if (wave == 0) {
#pragma unroll
    for (int m = 0; m < 2; m++)
#pragma unroll
      for (int j = 0; j < 4; j++) {
        float L = lsum[m][j];
        float wt[3];
#pragma unroll
        for (int w = 0; w < 3; w++) {
          wt[w] = MBl[w][lane][m * 4 + j];
          L += wt[w];
        }
        float invL = 1.f / L;
#pragma unroll
        for (int n = 0; n < 4; n++) {
          float val = oacc[m][n][j];
#pragma unroll
          for (int w = 0; w < 3; w++)
            val += (float)MBo[w][lane][m * 16 + n * 4 + j] * wt[w];
          o[(size_t)(q0 + m * 16 + lk * 4 + j) * DIM + hh * 64 + n * 16 +
            lr] = (f16)(val * invL);
        }
      }
  }
}

extern "C" void kernel_launch(void* const* d_in, const int* in_sizes, int n_in,
                              void* d_out, int out_size, void* d_ws,
                              size_t ws_size, hipStream_t stream) {
  (void)in_sizes; (void)n_in; (void)out_size; (void)ws_size;
  const int* tokens = (const int*)d_in[0];
  const float* emb = (const float*)d_in[1];
  const float* wq = (const float*)d_in[2];
  const float* wk = (const float*)d_in[3];
  const float* wv = (const float*)d_in[4];
  const float* wo = (const float*)d_in[5];
  const float* w1 = (const float*)d_in[6];
  const float* w2 = (const float*)d_in[7];
  const float* w3 = (const float*)d_in[8];
  const float* anw = (const float*)d_in[9];
  const float* fnw = (const float*)d_in[10];
  const float* finw = (const float*)d_in[11];
  float* out = (float*)d_out;

  char* p = (char*)d_ws;
  auto alloc = [&](size_t bytes) {
    char* r = p;
    p += (bytes + 255) & ~(size_t)255;
    return r;
  };
  f16* wqkv_l = (f16*)alloc((size_t)3 * DIM * DIM * 2);
  f16* wo_l = (f16*)alloc((size_t)DIM * DIM * 2);
  f16* w13_l = (f16*)alloc((size_t)2 * HIDD * DIM * 2);
  f16* w2_l = (f16*)alloc((size_t)DIM * HIDD * 2);
  float* hbuf = (float*)alloc((size_t)SEQ * DIM * 4);
  f16* x_h = (f16*)alloc((size_t)SEQ * DIM * 2);
  f16* qkv_h = (f16*)alloc((size_t)SEQ * 3 * DIM * 2);
  f16* vT_h = (f16*)alloc((size_t)DIM * SEQ * 2);
  f16* o_h = (f16*)alloc((size_t)SEQ * DIM * 2);
  f16* t_h = (f16*)alloc((size_t)SEQ * HIDD * 2);
  float* skbuf = (float*)alloc((size_t)2 * SEQ * DIM * 4);
  float* tab = (float*)alloc((size_t)SEQ * 32 * 2 * 4);
  float* hn = (float*)alloc(4096);

  embed_k<<<SEQ, 256, 0, stream>>>(tokens, emb, hbuf);
  rope_tab_k<<<(SEQ * 32 + 255) / 256, 256, 0, stream>>>(tab);

  const int CAST_BLOCKS = (4 * (DIM * DIM / 4) + 3 * (HIDD * DIM / 4)) / 256;
  for (int l = 0; l < LNUM; l++) {
    const size_t offDD = (size_t)l * DIM * DIM;
    const size_t offHD = (size_t)l * HIDD * DIM;
    cast_layer_k<<<CAST_BLOCKS, 256, 0, stream>>>(
        wq + offDD, wk + offDD, wv + offDD, wo + offDD, w1 + offHD,
        w3 + offHD, w2 + offHD, wqkv_l, wo_l, w13_l, w2_l);

    if (l == 0) {
      rmsnorm_k<<<SEQ, 256, 0, stream>>>(hbuf, anw, x_h);
    } else {
      rmsnorm_sk<<<SEQ, 256, 0, stream>>>(hbuf, skbuf, anw + (size_t)l * DIM,
                                          x_h);
    }
    {
      dim3 g(SEQ / 128, (3 * DIM) / 128);
      gemm_qkv<<<g, 256, 0, stream>>>(x_h, wqkv_l, qkv_h, vT_h, tab);
    }
    {
      dim3 g(NH, SEQ / 32);  // head-major, qb=63-y heavy-first
      attn_k<<<g, 256, 0, stream>>>(qkv_h, vT_h, o_h);
    }
    {
      // O-proj split-K: K=1024 -> 2x512 (partials folded by rmsnorm_sk)
      dim3 g(SEQ / 128, DIM / 128, 2);
      gemm_skp<<<g, 256, 0, stream>>>(o_h, wo_l, skbuf, DIM, DIM, DIM / 2);
    }
    rmsnorm_sk<<<SEQ, 256, 0, stream>>>(hbuf, skbuf, fnw + (size_t)l * DIM,
                                        x_h);
    {
      // fused W13 (interleaved) + silu
      dim3 g(SEQ / 128, (2 * HIDD) / 128);
      gemm_w13i<<<g, 256, 0, stream>>>(x_h, w13_l, t_h);
    }
    {
      // W2 split-K: K=2816 -> 2x1408 (partials folded by next norm)
      dim3 g(SEQ / 128, DIM / 128, 2);
      gemm_skp<<<g, 256, 0, stream>>>(t_h, w2_l, skbuf, DIM, HIDD, HIDD / 2);
    }
  }
  final_norm_sk<<<1, 256, 0, stream>>>(hbuf, skbuf, finw, hn);
  logits_k<<<VOCAB / 4, 256, 0, stream>>>(hn, emb, out);
}